// Round 3
// baseline (713.998 us; speedup 1.0000x reference)
//
#include <hip/hip_runtime.h>

#define NPTS (16*20480)
#define BM 32
#define NTILES (NPTS/BM)   // 10240
#define GRID 256

typedef _Float16 f16;
typedef _Float16 f16x4 __attribute__((ext_vector_type(4)));
typedef _Float16 f16x8 __attribute__((ext_vector_type(8)));
typedef float    f32x4 __attribute__((ext_vector_type(4)));

#define O_PTS   ((size_t)0)
#define O_GRASP ((size_t)NPTS*3)
#define O_S     (O_GRASP + (size_t)NPTS*16)
#define O_W     (O_S + (size_t)NPTS)
#define O_FEAT  (O_W + (size_t)NPTS)

struct Params {
  const float* point_feat;
  const float* points;
  const float* W1[4];
  const float* b1[4];
  const float* W2[4];
  const float* b2[4];
  float* out;
};

__launch_bounds__(1024, 4)
__global__ void contactnet_fused(Params P)
{
  // LDS ~42 KB
  __shared__ f16   afh[2][BM][136];   // A hi, f16, stride 272B (2-way free)
  __shared__ f16   afl[2][BM][136];   // A lo
  __shared__ float xyzs[2][BM][3];    // exact fp32 xyz
  __shared__ float out2[BM][33];      // col = o*4 + q (padded stride 33)
  __shared__ float gr[BM][16];
  __shared__ float b2s[8];

  const int t    = threadIdx.x;
  const int lane = t & 63;
  const int wv   = t >> 6;     // 0..15
  const int head = wv >> 2;    // 0..3
  const int q    = wv & 3;     // quarter of 128 hidden
  const int l15  = lane & 15;
  const int lg   = lane >> 4;

  if (t < 8) { int o = t, hd = (o + 2) / 3, r = o - (hd ? 3*hd - 2 : 0); b2s[o] = P.b2[hd][r]; }

  // ---- layer-1 weights -> registers, split fp16 hi/lo (feat cols 3..130).
  float bias1[2], w1x[2], w1y[2], w1z[2];
  f16x8 Whi[2][4], Wlo[2][4];   // [nt][kk]
  {
    const float* W1h = P.W1[head];
    const float* b1h = P.b1[head];
    #pragma unroll
    for (int nt = 0; nt < 2; ++nt) {
      int row = q*32 + nt*16 + l15;
      const float* wr = W1h + row*131;
      bias1[nt] = b1h[row];
      w1x[nt] = wr[0]; w1y[nt] = wr[1]; w1z[nt] = wr[2];
      #pragma unroll
      for (int kk = 0; kk < 4; ++kk) {
        f16x8 fh, fl;
        #pragma unroll
        for (int j = 0; j < 8; ++j) {
          float w = wr[3 + kk*32 + lg*8 + j];
          f16 hi = (f16)w;
          fh[j] = hi; fl[j] = (f16)(w - (float)hi);
        }
        Whi[nt][kk] = fh; Wlo[nt][kk] = fl;
      }
    }
  }
  // ---- layer-2 weights -> registers
  const int goff = (head==0) ? 0 : (head==1) ? 1 : (head==2) ? 4 : 7;
  const int od   = (head==1 || head==2) ? 3 : 1;
  float W2r[3][2];
  #pragma unroll
  for (int ol = 0; ol < 3; ++ol)
    #pragma unroll
    for (int nt = 0; nt < 2; ++nt)
      W2r[ol][nt] = (ol < od) ? P.W2[head][ol*128 + q*32 + nt*16 + l15] : 0.f;

  const int p_  = t >> 5;     // staging: point 0..31
  const int c4_ = t & 31;     // staging: float4 index 0..31

  // ---- prologue: stage first tile
  int tile = blockIdx.x;
  {
    f32x4 v = *(const f32x4*)(P.point_feat + ((size_t)(tile*BM + p_)*128 + c4_*4));
    float xv = (t < 96) ? P.points[(size_t)tile*BM*3 + t] : 0.f;
    f16x4 hs, ls;
    #pragma unroll
    for (int j = 0; j < 4; ++j) { f16 hi = (f16)v[j]; hs[j] = hi; ls[j] = (f16)(v[j] - (float)hi); }
    *(f16x4*)&afh[0][p_][c4_*4] = hs;
    *(f16x4*)&afl[0][p_][c4_*4] = ls;
    float* dst = P.out + O_FEAT + (size_t)(tile*BM + p_)*131 + 3 + c4_*4;
    dst[0] = v[0]; dst[1] = v[1]; dst[2] = v[2]; dst[3] = v[3];
    if (t < 96) {
      int pp = t / 3, c = t - pp*3;
      xyzs[0][pp][c] = xv;
      P.out[O_PTS + (size_t)tile*BM*3 + t] = xv;
      P.out[O_FEAT + (size_t)(tile*BM + pp)*131 + c] = xv;
    }
  }
  __syncthreads();

  int cur = 0;
  for (;;) {
    const int base = tile * BM;
    const int nxt  = tile + GRID;
    const bool has = (nxt < NTILES);

    // ---- issue prefetch loads for next tile (latency hidden under MFMA)
    f32x4 pv = {0,0,0,0};
    float pxyz = 0.f;
    if (has) {
      pv = *(const f32x4*)(P.point_feat + ((size_t)(nxt*BM + p_)*128 + c4_*4));
      if (t < 96) pxyz = P.points[(size_t)nxt*BM*3 + t];
    }

    // ---- layer 1: split-fp16 MFMA 16x16x32, per wave 32pts x 32hid
    f32x4 acc[2][2];
    #pragma unroll
    for (int mt = 0; mt < 2; ++mt)
      #pragma unroll
      for (int nt = 0; nt < 2; ++nt) {
        acc[mt][nt][0] = bias1[nt]; acc[mt][nt][1] = bias1[nt];
        acc[mt][nt][2] = bias1[nt]; acc[mt][nt][3] = bias1[nt];
      }
    // xyz contribution, exact fp32 VALU (C/D: row=lg*4+r, col=l15)
    #pragma unroll
    for (int mt = 0; mt < 2; ++mt)
      #pragma unroll
      for (int r = 0; r < 4; ++r) {
        int m = mt*16 + lg*4 + r;
        float x = xyzs[cur][m][0], y = xyzs[cur][m][1], z = xyzs[cur][m][2];
        #pragma unroll
        for (int nt = 0; nt < 2; ++nt)
          acc[mt][nt][r] += x*w1x[nt] + y*w1y[nt] + z*w1z[nt];
      }
    #pragma unroll
    for (int kk = 0; kk < 4; ++kk) {
      f16x8 ah[2], al[2];
      #pragma unroll
      for (int mt = 0; mt < 2; ++mt) {
        int m  = mt*16 + l15;
        int k0 = kk*32 + lg*8;
        ah[mt] = *(const f16x8*)&afh[cur][m][k0];
        al[mt] = *(const f16x8*)&afl[cur][m][k0];
      }
      #pragma unroll
      for (int mt = 0; mt < 2; ++mt)
        #pragma unroll
        for (int nt = 0; nt < 2; ++nt) {
          acc[mt][nt] = __builtin_amdgcn_mfma_f32_16x16x32_f16(ah[mt], Whi[nt][kk], acc[mt][nt], 0, 0, 0);
          acc[mt][nt] = __builtin_amdgcn_mfma_f32_16x16x32_f16(al[mt], Whi[nt][kk], acc[mt][nt], 0, 0, 0);
          acc[mt][nt] = __builtin_amdgcn_mfma_f32_16x16x32_f16(ah[mt], Wlo[nt][kk], acc[mt][nt], 0, 0, 0);
        }
    }

    // ---- layer 2 in-register: relu -> partial over nt -> butterfly over l15
    #pragma unroll
    for (int ol = 0; ol < 3; ++ol) {
      if (ol < od) {
        #pragma unroll
        for (int mt = 0; mt < 2; ++mt)
          #pragma unroll
          for (int r = 0; r < 4; ++r) {
            float v = 0.f;
            #pragma unroll
            for (int nt = 0; nt < 2; ++nt)
              v = fmaf(W2r[ol][nt], fmaxf(acc[mt][nt][r], 0.f), v);
            v += __shfl_xor(v, 1);
            v += __shfl_xor(v, 2);
            v += __shfl_xor(v, 4);
            v += __shfl_xor(v, 8);
            if (l15 == 0)
              out2[mt*16 + lg*4 + r][(goff + ol)*4 + q] = v;
          }
      }
    }

    // ---- stage next tile from prefetched regs
    if (has) {
      f16x4 hs, ls;
      #pragma unroll
      for (int j = 0; j < 4; ++j) { f16 hi = (f16)pv[j]; hs[j] = hi; ls[j] = (f16)(pv[j] - (float)hi); }
      *(f16x4*)&afh[cur^1][p_][c4_*4] = hs;
      *(f16x4*)&afl[cur^1][p_][c4_*4] = ls;
      float* dst = P.out + O_FEAT + (size_t)(nxt*BM + p_)*131 + 3 + c4_*4;
      dst[0] = pv[0]; dst[1] = pv[1]; dst[2] = pv[2]; dst[3] = pv[3];
      if (t < 96) {
        int pp = t / 3, c = t - pp*3;
        xyzs[cur^1][pp][c] = pxyz;
        P.out[O_PTS + (size_t)nxt*BM*3 + t] = pxyz;
        P.out[O_FEAT + (size_t)(nxt*BM + pp)*131 + c] = pxyz;
      }
    }
    __syncthreads();   // B1: out2 ready, next tile staged

    // ---- post-processing (fp32, 32 threads)
    if (t < BM) {
      const int p = t;
      float o_[8];
      #pragma unroll
      for (int o = 0; o < 8; ++o)
        o_[o] = b2s[o] + out2[p][o*4+0] + out2[p][o*4+1] + out2[p][o*4+2] + out2[p][o*4+3];
      float s = o_[0];
      float z1x = o_[1], z1y = o_[2], z1z = o_[3];
      float z2x = o_[4], z2y = o_[5], z2z = o_[6];
      float w   = o_[7];
      float px = xyzs[cur][p][0], py = xyzs[cur][p][1], pz = xyzs[cur][p][2];

      float n1 = sqrtf(z1x*z1x + z1y*z1y + z1z*z1z);
      z1x /= n1; z1y /= n1; z1z /= n1;
      float d12 = z1x*z2x + z1y*z2y + z1z*z2z;
      z2x -= d12*z1x; z2y -= d12*z1y; z2z -= d12*z1z;
      float n2 = sqrtf(z2x*z2x + z2y*z2y + z2z*z2z);
      z2x /= n2; z2y /= n2; z2z /= n2;
      w = fminf(fmaxf(w, -0.08f), 0.08f);

      float nb = sqrtf(z1x*z1x + z1y*z1y + z1z*z1z);
      float bx = z1x/nb, by = z1y/nb, bz = z1z/nb;
      float inner = bx*z2x + by*z2y + bz*z2z;
      float na2 = sqrtf(z2x*z2x + z2y*z2y + z2z*z2z);
      float ax = (z2x - inner*bx)/na2, ay = (z2y - inner*by)/na2, az = (z2z - inner*bz)/na2;
      float nbn = sqrtf(bx*bx + by*by + bz*bz);
      float bnx = bx/nbn, bny = by/nbn, bnz = bz/nbn;
      float nan2 = sqrtf(ax*ax + ay*ay + az*az);
      float anx = ax/nan2, any_ = ay/nan2, anz = az/nan2;
      float cx = any_*bnz - anz*bny;
      float cy = anz*bnx - anx*bnz;
      float cz = anx*bny - any_*bnx;
      float nc = sqrtf(cx*cx + cy*cy + cz*cz);
      float gx = cx/nc, gyv = cy/nc, gzv = cz/nc;
      float tx = px - 0.1034f*anx + 0.5f*w*bnx;
      float ty = py - 0.1034f*any_ + 0.5f*w*bny;
      float tz = pz - 0.1034f*anz + 0.5f*w*bnz;

      gr[p][0]=bnx; gr[p][1]=gx;  gr[p][2]=anx;  gr[p][3]=tx;
      gr[p][4]=bny; gr[p][5]=gyv; gr[p][6]=any_; gr[p][7]=ty;
      gr[p][8]=bnz; gr[p][9]=gzv; gr[p][10]=anz; gr[p][11]=tz;
      gr[p][12]=0.f; gr[p][13]=0.f; gr[p][14]=0.f; gr[p][15]=1.f;

      P.out[O_S + base + p] = s;
      P.out[O_W + base + p] = fmaxf(w, 0.f);
    }
    __syncthreads();   // B2: gr ready

    if (t < 512)
      P.out[O_GRASP + (size_t)base*16 + t] = gr[t >> 4][t & 15];

    if (!has) break;
    tile = nxt; cur ^= 1;
  }
}

extern "C" void kernel_launch(void* const* d_in, const int* in_sizes, int n_in,
                              void* d_out, int out_size, void* d_ws, size_t ws_size,
                              hipStream_t stream) {
  Params P;
  P.point_feat = (const float*)d_in[0];
  P.points     = (const float*)d_in[1];
  // d_in[2] = batch ids (unused; B is static)
  int idx = 3;
  for (int h = 0; h < 4; ++h) {
    P.W1[h] = (const float*)d_in[idx + 0];
    P.b1[h] = (const float*)d_in[idx + 1];
    P.W2[h] = (const float*)d_in[idx + 2];
    P.b2[h] = (const float*)d_in[idx + 3];
    idx += 4;
  }
  P.out = (float*)d_out;
  contactnet_fused<<<dim3(GRID), dim3(1024), 0, stream>>>(P);
}